// Round 8
// baseline (499.574 us; speedup 1.0000x reference)
//
#include <hip/hip_runtime.h>
#include <hip/hip_bf16.h>
#include <type_traits>

#define DEVINL __device__ __forceinline__

typedef float f32x4 __attribute__((ext_vector_type(4)));
typedef __bf16 bf16x8 __attribute__((ext_vector_type(8)));

DEVINL float bf2f(short s) {
  unsigned u = ((unsigned)(unsigned short)s) << 16;
  float f; __builtin_memcpy(&f, &u, 4); return f;
}
DEVINL short f2bf(float f) {
  unsigned u; __builtin_memcpy(&u, &f, 4);
  u += 0x7fff + ((u >> 16) & 1);          // round-nearest-even
  return (short)(u >> 16);
}

DEVINL void gl_lds16(const void* g, void* l) {
  __builtin_amdgcn_global_load_lds(
      (const __attribute__((address_space(1))) void*)g,
      (__attribute__((address_space(3))) void*)l, 16, 0, 0);
}

// XCD-aware block swizzle (T1, m192).  R2: gemm_sk FETCH 276 MB -> 68 MB.
// Requires nwg % 8 == 0 (grids: 1024/512/256/16).
DEVINL void swz_blk(int& bx, int& by, int& bz) {
  const int gx = gridDim.x, gy = gridDim.y;
  const int tpz = gx * gy;
  const int nwg = tpz * gridDim.z;
  int fid = bx + gx * (by + gy * bz);
  fid = (fid & 7) * (nwg >> 3) + (fid >> 3);
  bz = fid / tpz;
  const int r = fid - bz * tpz;
  by = r % gy;            // m fastest: consecutive blocks share the B n-panel
  bx = r / gy;
}

// ---------- 128x128 tile / 256-thread path (small GEMMs) ----------

template <typename OutT, bool BIAS, bool EXP>
DEVINL void epilogue_store(f32x4 (&acc)[4][4], char* smem,
                           OutT* __restrict__ C, int ldc, int m0, int n0,
                           const float* __restrict__ bias,
                           float* __restrict__ rowsum, int t) {
  const int wave = t >> 6, lane = t & 63;
  const int quad = lane >> 4, l16 = lane & 15;
  const int arow = (wave >> 1) * 64, brow = (wave & 1) * 64;
  if constexpr (std::is_same<OutT, float>::value) {
    float* tile = (float*)smem;          // 64 x 128 fp32 per round
#pragma unroll
    for (int rnd = 0; rnd < 2; ++rnd) {
      if ((arow >> 6) == rnd) {
#pragma unroll
        for (int mi = 0; mi < 4; ++mi)
#pragma unroll
          for (int ni = 0; ni < 4; ++ni) {
            const int col = brow + ni * 16 + l16;
#pragma unroll
            for (int r = 0; r < 4; ++r) {
              const int row = mi * 16 + quad * 4 + r;
              float v = acc[mi][ni][r];
              if (BIAS) v += bias[m0 + rnd * 64 + row];
              tile[row * 128 + col] = v;
            }
          }
      }
      __syncthreads();
#pragma unroll
      for (int i = 0; i < 8; ++i) {
        const int row = wave * 16 + i * 2 + (lane >> 5);
        const int cf  = (lane & 31) * 4;
        f32x4 v = *(f32x4*)&tile[row * 128 + cf];
        *(f32x4*)&C[(long)(m0 + rnd * 64 + row) * ldc + n0 + cf] = v;
      }
      __syncthreads();
    }
  } else {
    short* tile = (short*)smem;          // 128 x 128 bf16
#pragma unroll
    for (int mi = 0; mi < 4; ++mi)
#pragma unroll
      for (int r = 0; r < 4; ++r) {
        const int row = arow + mi * 16 + quad * 4 + r;
        float rs = 0.f;
#pragma unroll
        for (int ni = 0; ni < 4; ++ni) {
          const int col = brow + ni * 16 + l16;
          float v = acc[mi][ni][r];
          if (BIAS) v += bias[m0 + row];
          if (EXP) { v = __expf(v); rs += v; }
          tile[row * 128 + col] = f2bf(v);
        }
        if (EXP) {
          rs += __shfl_xor(rs, 1); rs += __shfl_xor(rs, 2);
          rs += __shfl_xor(rs, 4); rs += __shfl_xor(rs, 8);
          if (l16 == 0) atomicAdd(&rowsum[m0 + row], rs);
        }
      }
    __syncthreads();
#pragma unroll
    for (int i = 0; i < 8; ++i) {
      const int row = wave * 32 + i * 4 + (lane >> 4);
      const int cs  = l16 * 8;
      int4 v = *(int4*)&tile[row * 128 + cs];
      *(int4*)&C[(long)(m0 + row) * ldc + n0 + cs] = v;
    }
  }
}

// 2-phase double-buffered K loop (small GEMMs, unchanged).
#define GEMM_K_LOOP(A_, lda_, B_, ldb_, kbeg_, kend_)                        \
  {                                                                          \
    const int lrow = t >> 2;                                                 \
    const int lk8  = (t & 3) * 8;                                            \
    auto stage = [&](int buf, int k0) {                                      \
      _Pragma("unroll")                                                      \
      for (int s = 0; s < 2; ++s) {                                          \
        gl_lds16(A_ + (long)(m0 + s * 64 + lrow) * lda_ + k0 + lk8,          \
                 smem + buf * 16384 + s * 4096 + wave * 1024);               \
        gl_lds16(B_ + (long)(n0 + s * 64 + lrow) * ldb_ + k0 + lk8,          \
                 smem + buf * 16384 + 8192 + s * 4096 + wave * 1024);        \
      }                                                                      \
    };                                                                       \
    stage(0, kbeg_);                                                         \
    __syncthreads();                                                         \
    int cur = 0;                                                             \
    for (int k0 = kbeg_; k0 < kend_; k0 += 32) {                             \
      if (k0 + 32 < kend_) stage(cur ^ 1, k0 + 32);                          \
      const short* As = (const short*)(smem + cur * 16384);                  \
      const short* Bs = (const short*)(smem + cur * 16384 + 8192);           \
      bf16x8 af[4], bfr[4];                                                  \
      _Pragma("unroll")                                                      \
      for (int i = 0; i < 4; ++i)                                            \
        af[i] = *(const bf16x8*)&As[(arow + i * 16 + l16) * 32 + quad * 8];  \
      _Pragma("unroll")                                                      \
      for (int i = 0; i < 4; ++i)                                            \
        bfr[i] = *(const bf16x8*)&Bs[(brow + i * 16 + l16) * 32 + quad * 8]; \
      _Pragma("unroll")                                                      \
      for (int mi = 0; mi < 4; ++mi)                                         \
        _Pragma("unroll")                                                    \
        for (int ni = 0; ni < 4; ++ni)                                       \
          acc[mi][ni] = __builtin_amdgcn_mfma_f32_16x16x32_bf16(             \
              af[mi], bfr[ni], acc[mi][ni], 0, 0, 0);                        \
      __syncthreads();                                                       \
      cur ^= 1;                                                              \
    }                                                                        \
  }

template <typename OutT, bool BIAS, bool EXP>
__global__ __launch_bounds__(256, 4)
void gemm_nt(const short* __restrict__ A, long sA, int lda,
             const short* __restrict__ B, long sB, int ldb,
             OutT* __restrict__ C, long sC, int ldc,
             const float* __restrict__ bias, float* __restrict__ rowsum, int K)
{
  int bx = blockIdx.x, by = blockIdx.y, bz = blockIdx.z;
  swz_blk(bx, by, bz);

  A += (long)bz * sA;
  B += (long)bz * sB;
  C += (long)bz * sC;
  if (EXP) rowsum += (long)bz * 512;

  __shared__ char smem[32768];

  const int t    = threadIdx.x;
  const int wave = t >> 6, lane = t & 63;
  const int quad = lane >> 4, l16 = lane & 15;
  const int m0 = by * 128, n0 = bx * 128;
  const int arow = (wave >> 1) * 64, brow = (wave & 1) * 64;

  f32x4 acc[4][4];
#pragma unroll
  for (int i = 0; i < 4; ++i)
#pragma unroll
    for (int j = 0; j < 4; ++j) acc[i][j] = (f32x4){0.f, 0.f, 0.f, 0.f};

  GEMM_K_LOOP(A, lda, B, ldb, 0, K)

  epilogue_store<OutT, BIAS, EXP>(acc, smem, C, ldc, m0, n0, bias, rowsum, t);
}

// ---------- 128x256 tile / 512-thread / 8-wave path (big GEMMs) ----------

template <typename OutT, bool BIAS, bool EXP>
DEVINL void epilogue_store_wide(f32x4 (&acc)[4][4], char* smem,
                                OutT* __restrict__ C, int ldc, int m0, int n0,
                                const float* __restrict__ bias,
                                float* __restrict__ rowsum, int t) {
  const int wave = t >> 6, lane = t & 63;
  const int quad = lane >> 4, l16 = lane & 15;
  const int arow = (wave >> 2) * 64, brow = (wave & 3) * 64;
  const int rn_w = brow >> 7;          // this wave's n-round
  const int colb = brow & 64;          // col base within the 128-wide round
  if constexpr (std::is_same<OutT, float>::value) {
    float* tile = (float*)smem;        // 64 x 128 fp32 per round
    const int rm_w = arow >> 6;
#pragma unroll
    for (int rm = 0; rm < 2; ++rm)
#pragma unroll
      for (int rn = 0; rn < 2; ++rn) {
        if (rm_w == rm && rn_w == rn) {
#pragma unroll
          for (int mi = 0; mi < 4; ++mi)
#pragma unroll
            for (int ni = 0; ni < 4; ++ni)
#pragma unroll
              for (int r = 0; r < 4; ++r) {
                const int row = mi * 16 + quad * 4 + r;
                float v = acc[mi][ni][r];
                if (BIAS) v += bias[m0 + rm * 64 + row];
                tile[row * 128 + colb + ni * 16 + l16] = v;
              }
        }
        __syncthreads();
#pragma unroll
        for (int i = 0; i < 4; ++i) {
          const int row = wave * 8 + i * 2 + (lane >> 5);
          const int cf  = (lane & 31) * 4;
          *(f32x4*)&C[(long)(m0 + rm * 64 + row) * ldc + n0 + rn * 128 + cf] =
              *(f32x4*)&tile[row * 128 + cf];
        }
        __syncthreads();
      }
  } else {
    if (EXP) {                         // exp + per-row sum atomics, in-place
#pragma unroll
      for (int mi = 0; mi < 4; ++mi)
#pragma unroll
        for (int r = 0; r < 4; ++r) {
          const int row = arow + mi * 16 + quad * 4 + r;
          float rs = 0.f;
#pragma unroll
          for (int ni = 0; ni < 4; ++ni) {
            float v = __expf(acc[mi][ni][r]);
            acc[mi][ni][r] = v; rs += v;
          }
          rs += __shfl_xor(rs, 1); rs += __shfl_xor(rs, 2);
          rs += __shfl_xor(rs, 4); rs += __shfl_xor(rs, 8);
          if (l16 == 0) atomicAdd(&rowsum[m0 + row], rs);
        }
    }
    short* tile = (short*)smem;        // 128 x 128 bf16 per round
#pragma unroll
    for (int rn = 0; rn < 2; ++rn) {
      if (rn_w == rn) {
#pragma unroll
        for (int mi = 0; mi < 4; ++mi)
#pragma unroll
          for (int ni = 0; ni < 4; ++ni)
#pragma unroll
            for (int r = 0; r < 4; ++r) {
              const int row = arow + mi * 16 + quad * 4 + r;
              float v = acc[mi][ni][r];
              if (BIAS) v += bias[m0 + row];
              tile[row * 128 + colb + ni * 16 + l16] = f2bf(v);
            }
      }
      __syncthreads();
#pragma unroll
      for (int i = 0; i < 4; ++i) {
        const int row = wave * 16 + i * 4 + (lane >> 4);
        const int cs  = l16 * 8;
        *(int4*)&C[(long)(m0 + row) * ldc + n0 + rn * 128 + cs] =
            *(int4*)&tile[row * 128 + cs];
      }
      __syncthreads();
    }
  }
}

// Shared stage/compute for the wide K loops.
#define WIDE_STAGE_COMPUTE(A_, lda_, B_, ldb_, BUFSZ_)                       \
    const int lrow = t >> 2;           /* 0..127 */                          \
    const int lk8  = (t & 3) * 8;                                            \
    auto stage = [&](int buf, int k0) {                                      \
      gl_lds16(A_ + (long)(m0 + lrow) * lda_ + k0 + lk8,                     \
               smem + buf * BUFSZ_ + wave * 1024);                           \
      _Pragma("unroll")                                                      \
      for (int s = 0; s < 2; ++s)                                            \
        gl_lds16(B_ + (long)(n0 + s * 128 + lrow) * ldb_ + k0 + lk8,         \
                 smem + buf * BUFSZ_ + 8192 + s * 8192 + wave * 1024);       \
    };                                                                       \
    auto compute = [&](int buf) {                                            \
      const short* As = (const short*)(smem + buf * BUFSZ_);                 \
      const short* Bs = (const short*)(smem + buf * BUFSZ_ + 8192);          \
      bf16x8 af[4], bfr[4];                                                  \
      _Pragma("unroll")                                                      \
      for (int i = 0; i < 4; ++i)                                            \
        af[i] = *(const bf16x8*)&As[(arow + i * 16 + l16) * 32 + quad * 8];  \
      _Pragma("unroll")                                                      \
      for (int i = 0; i < 4; ++i)                                            \
        bfr[i] = *(const bf16x8*)&Bs[(brow + i * 16 + l16) * 32 + quad * 8]; \
      _Pragma("unroll")                                                      \
      for (int mi = 0; mi < 4; ++mi)                                         \
        _Pragma("unroll")                                                    \
        for (int ni = 0; ni < 4; ++ni)                                       \
          acc[mi][ni] = __builtin_amdgcn_mfma_f32_16x16x32_bf16(             \
              af[mi], bfr[ni], acc[mi][ni], 0, 0, 0);                        \
    };

// counted-vmcnt 3-buffer pipeline (depth 2) — exp/final GEMMs (2 blocks/CU).
#define WIDE_K_LOOP(A_, lda_, B_, ldb_, kbeg_, kend_)                        \
  {                                                                          \
    WIDE_STAGE_COMPUTE(A_, lda_, B_, ldb_, 24576)                            \
    stage(0, kbeg_);                                                         \
    stage(1, kbeg_ + 32);                                                    \
    int cur = 0;                                                             \
    for (int k0 = kbeg_; k0 < kend_ - 32; k0 += 32) {                        \
      asm volatile("s_waitcnt vmcnt(3)" ::: "memory");                       \
      __builtin_amdgcn_s_barrier();                                          \
      __builtin_amdgcn_sched_barrier(0);                                     \
      if (k0 + 64 < kend_) {                                                 \
        int nb = cur + 2; if (nb >= 3) nb -= 3;                              \
        stage(nb, k0 + 64);                                                  \
      }                                                                      \
      compute(cur);                                                          \
      ++cur; if (cur == 3) cur = 0;                                          \
    }                                                                        \
    asm volatile("s_waitcnt vmcnt(0)" ::: "memory");                         \
    __builtin_amdgcn_s_barrier();                                            \
    __builtin_amdgcn_sched_barrier(0);                                       \
    compute(cur);                                                            \
    __syncthreads();                   /* protect epilogue smem reuse */     \
  }

// R8: counted-vmcnt 4-buffer depth-3 pipeline — gemm_sk (1 block/CU, LDS
// free).  stage(t+3) targets buf (t-1)&3 whose ds_reads completed before
// this iteration's barrier (R5 argument, one step deeper).  Tail peels
// vmcnt by remaining K: rem>=96 -> 6 (2 stages in flight), rem==64 -> 3,
// rem==32 -> 0.
#define WIDE4_K_LOOP(A_, lda_, B_, ldb_, kbeg_, kend_)                       \
  {                                                                          \
    WIDE_STAGE_COMPUTE(A_, lda_, B_, ldb_, 24576)                            \
    stage(0, kbeg_);                                                         \
    stage(1, kbeg_ + 32);                                                    \
    stage(2, kbeg_ + 64);                                                    \
    int cur = 0;                                                             \
    for (int k0 = kbeg_; k0 < kend_; k0 += 32) {                             \
      const int rem = kend_ - k0;                                            \
      if (rem >= 96)      asm volatile("s_waitcnt vmcnt(6)" ::: "memory");   \
      else if (rem == 64) asm volatile("s_waitcnt vmcnt(3)" ::: "memory");   \
      else                asm volatile("s_waitcnt vmcnt(0)" ::: "memory");   \
      __builtin_amdgcn_s_barrier();                                          \
      __builtin_amdgcn_sched_barrier(0);                                     \
      if (rem > 96) stage((cur + 3) & 3, k0 + 96);                           \
      compute(cur);                                                          \
      cur = (cur + 1) & 3;                                                   \
    }                                                                        \
    __syncthreads();                   /* protect epilogue smem reuse */     \
  }

template <typename OutT, bool BIAS, bool EXP>
__global__ __launch_bounds__(512, 4)
void gemm_nt_wide(const short* __restrict__ A, long sA, int lda,
                  const short* __restrict__ B, long sB, int ldb,
                  OutT* __restrict__ C, long sC, int ldc,
                  const float* __restrict__ bias, float* __restrict__ rowsum,
                  int K)
{
  int bx = blockIdx.x, by = blockIdx.y, bz = blockIdx.z;
  swz_blk(bx, by, bz);

  A += (long)bz * sA;
  B += (long)bz * sB;
  C += (long)bz * sC;
  if (EXP) rowsum += (long)bz * 512;

  __shared__ char smem[73728];         // 3x24KB staging; epilogue uses 32KB

  const int t    = threadIdx.x;
  const int wave = t >> 6, lane = t & 63;
  const int quad = lane >> 4, l16 = lane & 15;
  const int m0 = by * 128, n0 = bx * 256;
  const int arow = (wave >> 2) * 64, brow = (wave & 3) * 64;

  f32x4 acc[4][4];
#pragma unroll
  for (int i = 0; i < 4; ++i)
#pragma unroll
    for (int j = 0; j < 4; ++j) acc[i][j] = (f32x4){0.f, 0.f, 0.f, 0.f};

  WIDE_K_LOOP(A, lda, B, ldb, 0, K)

  epilogue_store_wide<OutT, BIAS, EXP>(acc, smem, C, ldc, m0, n0, bias,
                                       rowsum, t);
}

// split-K wide: M=512, N=512, K=4096 in 2 chunks of 2048, fp32 partials.
__global__ __launch_bounds__(512, 2)
void gemm_sk_wide(const short* __restrict__ Ab, const short* __restrict__ Bb,
                  float* __restrict__ Cp)
{
  int bx = blockIdx.x, by = blockIdx.y, bz = blockIdx.z;
  swz_blk(bx, by, bz);

  const int b = bz >> 1, s = bz & 1;
  const short* A = Ab + (long)b * 2097152;
  const short* B = Bb + (long)b * 2097152;
  float* C = Cp + (long)(s * 16 + b) * 262144;

  __shared__ char smem[98304];         // 4x24KB staging (1 block/CU)

  const int t    = threadIdx.x;
  const int wave = t >> 6, lane = t & 63;
  const int quad = lane >> 4, l16 = lane & 15;
  const int m0 = by * 128, n0 = bx * 256;
  const int arow = (wave >> 2) * 64, brow = (wave & 3) * 64;
  const int kbeg = s * 2048, kend = kbeg + 2048;

  f32x4 acc[4][4];
#pragma unroll
  for (int i = 0; i < 4; ++i)
#pragma unroll
    for (int j = 0; j < 4; ++j) acc[i][j] = (f32x4){0.f, 0.f, 0.f, 0.f};

  WIDE4_K_LOOP(A, 4096, B, 4096, kbeg, kend)

  epilogue_store_wide<float, false, false>(acc, smem, C, 512, m0, n0, nullptr,
                                           nullptr, t);
}

// sum 2 fp32 split-K partials, normalize by 1/rowsum (softmax denom) -> bf16
__global__ void reduce_sk(const float* __restrict__ p, short* __restrict__ o,
                          const float* __restrict__ s) {
  const long i = ((long)blockIdx.x * 256 + threadIdx.x) * 4;
  const float inv = 1.f / s[i >> 9];     // i/512 = b*512 + d
  f32x4 a = *(const f32x4*)&p[i];
  f32x4 b = *(const f32x4*)&p[i + 4194304];
  short r[4];
#pragma unroll
  for (int j = 0; j < 4; ++j) r[j] = f2bf((a[j] + b[j]) * inv);
  *(long*)&o[i] = *(long*)r;
}

// R8: prep_x — one pass over x producing xb (cast) + xT (transpose) via
// register-only 8x8 blocklets; removes cast_bf16's 64 MB xb re-read.
__global__ void prep_x(const float* __restrict__ x, short* __restrict__ xb,
                       short* __restrict__ xT) {
  const long g = (long)blockIdx.x * 256 + threadIdx.x;
  const int c8 = (int)(g & 63);            // 64 c-blocklets
  const int l8 = (int)((g >> 6) & 511);    // 512 l-blocklets
  const int b  = (int)(g >> 15);           // 16 batches
  const float* src = x + ((long)b << 21) + (long)(c8 * 8) * 4096 + l8 * 8;

  f32x4 lo[8], hi[8];
#pragma unroll
  for (int i = 0; i < 8; ++i) {
    lo[i] = *(const f32x4*)(src + (long)i * 4096);
    hi[i] = *(const f32x4*)(src + (long)i * 4096 + 4);
  }
  __builtin_amdgcn_sched_barrier(0);   // all 16 loads in flight first

  short s[8][8];
#pragma unroll
  for (int i = 0; i < 8; ++i)
#pragma unroll
    for (int j = 0; j < 4; ++j) {
      s[i][j]     = f2bf(lo[i][j]);
      s[i][4 + j] = f2bf(hi[i][j]);
    }

  short* db = xb + ((long)b << 21) + (long)(c8 * 8) * 4096 + l8 * 8;
#pragma unroll
  for (int i = 0; i < 8; ++i)
    *(int4*)(db + (long)i * 4096) = *(int4*)s[i];

  short* dt = xT + ((long)b << 21) + (long)(l8 * 8) * 512 + c8 * 8;
#pragma unroll
  for (int j = 0; j < 8; ++j) {
    short o[8];
#pragma unroll
    for (int i = 0; i < 8; ++i) o[i] = s[i][j];
    *(int4*)(dt + (long)j * 512) = *(int4*)o;
  }
}

// R8: prep_w — merged weight prep: blocks 0..4095 cast w_qkv/w_out to bf16
// (blocks 0..31 also zero ssum); blocks 4096..4607 transpose w_q -> wqT and
// w_v -> wvT (both from fp32 source; bf16-round once, identical numerics).
__global__ void prep_w(const float* __restrict__ wq, short* __restrict__ wqb,
                       const float* __restrict__ wo, short* __restrict__ wob,
                       float* __restrict__ ssum, short* __restrict__ wqT,
                       short* __restrict__ wvT) {
  __shared__ float tile[32][33];
  const int blk = blockIdx.x, t = threadIdx.x;
  if (blk < 4096) {
    const int i = blk * 256 + t;
    if (blk < 32) ssum[i] = 0.f;
    if (i < 786432) wqb[i] = f2bf(wq[i]);
    else            wob[i - 786432] = f2bf(wo[i - 786432]);
  } else {
    const int s = blk - 4096;                  // 0..511
    const float* src = (s >> 8) ? wq + 524288 : wq;   // w_v : w_q
    short* dst = (s >> 8) ? wvT : wqT;
    const int b2 = s & 255;
    const int c0 = (b2 & 15) * 32, r0 = (b2 >> 4) * 32;
    const int tx = t & 31, ty = t >> 5;
#pragma unroll
    for (int i = 0; i < 4; ++i)
      tile[ty + i * 8][tx] = src[(r0 + ty + i * 8) * 512 + c0 + tx];
    __syncthreads();
#pragma unroll
    for (int i = 0; i < 4; ++i)
      dst[(c0 + ty + i * 8) * 512 + r0 + tx] = f2bf(tile[tx][ty + i * 8]);
  }
}

extern "C" void kernel_launch(void* const* d_in, const int* in_sizes, int n_in,
                              void* d_out, int out_size, void* d_ws, size_t ws_size,
                              hipStream_t stream) {
  // B=16, C=512, L=4096
  const float* x     = (const float*)d_in[0];
  const float* w_qkv = (const float*)d_in[1];
  const float* w_out = (const float*)d_in[2];
  const float* b_out = (const float*)d_in[3];
  float* out = (float*)d_out;

  const long CL = (long)512 * 4096;   // 2,097,152 per-batch elems
  const long CC = (long)512 * 512;

  char* ws = (char*)d_ws;
  short* xT  = (short*)(ws);                 //  67,108,864 B  [b][l][c]
  short* xb  = (short*)(ws + 67108864);      //  67,108,864 B  [b][c][l]
  short* kbf = (short*)(ws + 134217728);     //  67,108,864 B  [b][d][l]  exp(k)
  float* Pp  = (float*)(ws + 201326592);     //  33,554,432 B  [s][b][d][c] fp32
  short* P   = (short*)(ws + 268435456);     //   8,388,608 B  [b][d][c]
  short* U   = (short*)(ws + 276824064);     //     524,288 B  U = w_o·w_v [o][c]
  short* wvT = (short*)(ws + 277348352);     //     524,288 B  w_v^T [c][e]
  short* M2  = (short*)(ws + 285212672);     //   8,388,608 B  [b][o][d]
  short* M3  = (short*)(ws + 293601280);     //   8,388,608 B  [b][o][c]
  short* wqb = (short*)(ws + 301989888);     //   1,572,864 B
  short* wob = (short*)(ws + 303562752);     //     524,288 B
  short* wqT = (short*)(ws + 304087040);     //     524,288 B  w_q^T [c][d]
  // ssum[b][d] (32 KB) aliases M3's region: M3 is first written AFTER
  // reduce_sk has consumed ssum (stream-ordered), so no conflict.
  float* ssum = (float*)(ws + 293601280);

  // weight prep (cast + both transposes + ssum zero) in one launch
  prep_w<<<4608, 256, 0, stream>>>(w_qkv, wqb, w_out, wob, ssum, wqT, wvT);

  // U[o][c] = sum_e w_o[o][e]·w_v[e][c]  (batch-independent fold:
  // M2 = w_o·ctx^T = (w_o·w_v)·P^T = U·P^T)
  gemm_nt<short, false, false><<<dim3(4, 4, 1), 256, 0, stream>>>(
      wob, 0, 512, wvT, 0, 512, U, 0, 512, nullptr, nullptr, 512);

  // xb = bf16(x) and xT = transpose(xb) in ONE pass over x
  prep_x<<<2048, 256, 0, stream>>>(x, xb, xT);

  // kbf[b][d][l] = exp(sum_c w_k[d][c]·xT[b][l][c]); ssum[b][d] = sum_l exp
  gemm_nt_wide<short, false, true><<<dim3(16, 4, 16), 512, 0, stream>>>(
      wqb + CC, 0, 512, xT, CL, 512, kbf, CL, 4096, nullptr, ssum, 512);

  // P[b][d][c] = (1/ssum[b][d]) * sum_l exp(k)[d][l]·xb[c][l]  (split-K 2)
  gemm_sk_wide<<<dim3(2, 4, 32), 512, 0, stream>>>(kbf, xb, Pp);
  reduce_sk<<<4096, 256, 0, stream>>>(Pp, P, ssum);

  // M2[b][o][d] = sum_c U[o][c]·P[b][d][c]   (M=N=512, K=512)
  gemm_nt<short, false, false><<<dim3(4, 4, 16), 256, 0, stream>>>(
      U, 0, 512, P, CC, 512, M2, CC, 512, nullptr, nullptr, 512);

  // M3[b][o][c] = sum_d M2[o][d]·wqT[c][d]   (M=N=512, K=512)
  gemm_nt<short, false, false><<<dim3(4, 4, 16), 256, 0, stream>>>(
      M2, CC, 512, wqT, 0, 512, M3, CC, 512, nullptr, nullptr, 512);

  // out[b][o][l] = sum_c M3[o][c]·xT[b][l][c] + b_out[o]  (fp32)
  gemm_nt_wide<float, true, false><<<dim3(16, 4, 16), 512, 0, stream>>>(
      M3, CC, 512, xT, CL, 512, out, CL, 4096, b_out, nullptr, 512);
}